// Round 17
// baseline (589.555 us; speedup 1.0000x reference)
//
#include <hip/hip_runtime.h>
#include <hip/hip_bf16.h>

typedef unsigned short u16;
typedef __bf16 bf16x8 __attribute__((ext_vector_type(8)));
typedef float  f32x4  __attribute__((ext_vector_type(4)));

__device__ __forceinline__ u16 f2bf(float f) {
    return __builtin_bit_cast(u16, (__bf16)f);
}
__device__ __forceinline__ float b2f(u16 u) {
    return __builtin_bit_cast(float, (unsigned)u << 16);
}
__device__ __forceinline__ f32x4 mfma16(bf16x8 a, bf16x8 b, f32x4 c) {
    return __builtin_amdgcn_mfma_f32_16x16x32_bf16(a, b, c, 0, 0, 0);
}
// async global->LDS, 16B per lane; LDS dest is wave-uniform base + lane*16
__device__ __forceinline__ void gl_lds16(const void* g, void* l) {
    __builtin_amdgcn_global_load_lds((const __attribute__((address_space(1))) void*)g,
                                     (__attribute__((address_space(3))) void*)l, 16, 0, 0);
}

// ---------------- fused preprocessing: hidden f32->bf16 cast + past-tail copy --------
__global__ void k_pre(const float* __restrict__ hidden, u16* __restrict__ hiddenB,
                      const float4* __restrict__ past, float4* __restrict__ present4) {
    int bx = blockIdx.x;
    if (bx < 16384) {
        long i = ((long)bx * 256 + threadIdx.x) * 4;
        float4 v = *(const float4*)(hidden + i);
        ushort4 o;
        o.x = f2bf(v.x); o.y = f2bf(v.y); o.z = f2bf(v.z); o.w = f2bf(v.w);
        *(ushort4*)(hiddenB + i) = o;
    } else {
        long i = (long)(bx - 16384) * 256 + threadIdx.x;   // 0 .. 2^21-1
        long g = i >> 16;                                  // plane index (32 planes)
        long inner = i & 65535;
        long off = g * 131072 + 65536 + inner;
        present4[off] = past[off];
    }
}

// ---------------- fused weight transpose+cast: Wq/Wk/Wv -> WqkvT, Wo -> WoT ----------
__global__ void k_transpose_all(const float* __restrict__ Wq, const float* __restrict__ Wk,
                                const float* __restrict__ Wv, const float* __restrict__ Wo,
                                u16* __restrict__ WqkvT, u16* __restrict__ WoT) {
    __shared__ float t[32][33];
    const int bx = blockIdx.x, k0 = blockIdx.y * 32;
    const float* src; u16* dst; int N; int col;
    if (bx < 128)      { src = Wq; N = 4096; col = bx * 32;         dst = WqkvT; }
    else if (bx < 160) { src = Wk; N = 1024; col = (bx - 128) * 32; dst = WqkvT + 4096L * 4096; }
    else if (bx < 192) { src = Wv; N = 1024; col = (bx - 160) * 32; dst = WqkvT + 5120L * 4096; }
    else               { src = Wo; N = 4096; col = (bx - 192) * 32; dst = WoT; }
    const int tx = threadIdx.x, ty = threadIdx.y;
    #pragma unroll
    for (int i = 0; i < 32; i += 8)
        t[ty + i][tx] = src[(long)(k0 + ty + i) * N + col + tx];
    __syncthreads();
    #pragma unroll
    for (int i = 0; i < 32; i += 8)
        dst[(long)(col + ty + i) * 4096 + k0 + tx] = f2bf(t[tx][ty + i]);
}

#define ABAR() do { __builtin_amdgcn_sched_barrier(0); __builtin_amdgcn_s_barrier(); \
                    __builtin_amdgcn_sched_barrier(0); } while (0)
#define LGKM0() do { asm volatile("s_waitcnt lgkmcnt(0)" ::: "memory"); \
                     __builtin_amdgcn_sched_barrier(0); } while (0)

// ================= m201-style 8-phase 256x256 GEMM (R15/R16-verified) =================
// C = A(MxK,bf16) * Bt(NxK,bf16)^T. BM=BN=256, BK=64, 512 thr = 8 waves (2M x 4N).
// LDS 128KB = {A,B} x 2dbuf x 2half x [128][64] bf16, chunk16 XOR swizzle.
// Quadrant rotation (0,0),(0,1),(1,0),(1,1); A frags held 2 phases, B held 4.
// vmcnt(8) once per K-tile; counted, never 0 in steady state (T3+T4+T5).
// NSPLIT: K-split; block 'half' covers K range [half*K/NSPLIT, +K/NSPLIT), writes
// bf16 partial to buffer half (consumer sums). QKV: 384 tiles x2 = 768 = 3.0 rounds.
template<int OBF16, int NSPLIT>
__global__ void __launch_bounds__(512, 2)
k_gemm8ph(const u16* __restrict__ A, const u16* __restrict__ Bt,
          void* __restrict__ Cv, int M, int N, int K, int gx)
{
    extern __shared__ u16 lds[];
    const int nwg = gridDim.x;
    const int bid = blockIdx.x;
    const int swzb = (bid & 7) * (nwg >> 3) + (bid >> 3);
    const int tiles = nwg / NSPLIT;
    const int half = swzb / tiles;
    const int tile = swzb % tiles;
    const long m0 = (long)(tile / gx) * 256;
    const long n0 = (long)(tile % gx) * 256;
    const int Klen = K / NSPLIT;
    const long kbase = (long)half * Klen;

    const int t = threadIdx.x;
    const int l = t & 63;
    const int w = t >> 6;
    const int wm = w >> 2, wn = w & 3;

    const int srow = t >> 3;
    const int scol = ((t & 7) ^ (srow & 7)) << 3;   // j-invariant (64 = 0 mod 8)
    const u16* aph[2] = { A  + (m0 + 0   + srow) * (long)K + kbase + scol,
                          A  + (m0 + 128 + srow) * (long)K + kbase + scol };
    const u16* bph[2] = { Bt + (n0 + 0   + srow) * (long)K + kbase + scol,
                          Bt + (n0 + 128 + srow) * (long)K + kbase + scol };

    const int swz0 = (((l >> 4) ^ (l & 7)) << 3);
    const int swz1 = ((((l >> 4) | 4) ^ (l & 7)) << 3);
    const int arowb = (wm * 64 + (l & 15)) * 64;    // + mf*1024
    const int browb = (wn * 32 + (l & 15)) * 64;    // + nf*1024

    f32x4 acc[8][4];
    #pragma unroll
    for (int i = 0; i < 8; ++i)
        #pragma unroll
        for (int j = 0; j < 4; ++j) acc[i][j] = (f32x4){0.f, 0.f, 0.f, 0.f};

    bf16x8 a[4][2], b0[2][2], b1[2][2];

    auto stA = [&](int d, int h, int kt) {
        const u16* s = aph[h] + (long)kt * 64;
        gl_lds16(s,              &lds[(d * 2 + h) * 8192 + t * 8]);
        gl_lds16(s + 64L * K,    &lds[(d * 2 + h) * 8192 + 4096 + t * 8]);
    };
    auto stB = [&](int d, int h, int kt) {
        const u16* s = bph[h] + (long)kt * 64;
        gl_lds16(s,              &lds[32768 + (d * 2 + h) * 8192 + t * 8]);
        gl_lds16(s + 64L * K,    &lds[32768 + (d * 2 + h) * 8192 + 4096 + t * 8]);
    };
    auto rdA = [&](int d, int h) {
        const int base = (d * 2 + h) * 8192;
        #pragma unroll
        for (int mf = 0; mf < 4; ++mf) {
            a[mf][0] = *(const bf16x8*)&lds[base + arowb + mf * 1024 + swz0];
            a[mf][1] = *(const bf16x8*)&lds[base + arowb + mf * 1024 + swz1];
        }
    };
    auto rdB = [&](int d, int h, bf16x8 (&bb)[2][2]) {
        const int base = 32768 + (d * 2 + h) * 8192;
        #pragma unroll
        for (int nf = 0; nf < 2; ++nf) {
            bb[nf][0] = *(const bf16x8*)&lds[base + browb + nf * 1024 + swz0];
            bb[nf][1] = *(const bf16x8*)&lds[base + browb + nf * 1024 + swz1];
        }
    };
    auto mfmaQ = [&](int qm, int qn, bf16x8 (&bb)[2][2]) {
        __builtin_amdgcn_s_setprio(1);
        #pragma unroll
        for (int mf = 0; mf < 4; ++mf)
            #pragma unroll
            for (int nf = 0; nf < 2; ++nf) {
                acc[qm * 4 + mf][qn * 2 + nf] =
                    mfma16(a[mf][0], bb[nf][0], acc[qm * 4 + mf][qn * 2 + nf]);
                acc[qm * 4 + mf][qn * 2 + nf] =
                    mfma16(a[mf][1], bb[nf][1], acc[qm * 4 + mf][qn * 2 + nf]);
            }
        __builtin_amdgcn_s_setprio(0);
        __builtin_amdgcn_sched_barrier(0);
    };

    const int nt = Klen >> 6;   // even (64 or 32)
    stA(0, 0, 0); stB(0, 0, 0); stB(0, 1, 0); stA(0, 1, 0);
    stA(1, 0, 1); stB(1, 0, 1); stB(1, 1, 1); stA(1, 1, 1);
    asm volatile("s_waitcnt vmcnt(8)" ::: "memory");
    __builtin_amdgcn_sched_barrier(0);
    __builtin_amdgcn_s_barrier();
    __builtin_amdgcn_sched_barrier(0);

    for (int kt = 0; kt < nt; kt += 2) {
        const bool g = (kt + 2) < nt;
        #pragma unroll
        for (int hh = 0; hh < 2; ++hh) {      // hh=0: dbuf0/tile kt; hh=1: dbuf1/kt+1
            const int d = hh;
            const int ktp = kt + 2 + hh;      // stage target tile
            // ---- phase 1: quadrant (0,0) ----
            rdA(d, 0); rdB(d, 0, b0);
            ABAR(); LGKM0();
            mfmaQ(0, 0, b0);
            ABAR();
            // ---- phase 2: quadrant (0,1); stage (ktp).A0,B0 ----
            rdB(d, 1, b1);
            if (g) { stA(d, 0, ktp); stB(d, 0, ktp); }
            ABAR(); LGKM0();
            mfmaQ(0, 1, b1);
            ABAR();
            // ---- phase 3: quadrant (1,0); stage (ktp).B1 ----
            rdA(d, 1);
            if (g) stB(d, 1, ktp);
            ABAR(); LGKM0();
            mfmaQ(1, 0, b0);
            ABAR();
            // ---- phase 4: quadrant (1,1); stage (ktp).A1; vmcnt(8) ----
            if (g) {
                stA(d, 1, ktp);
                asm volatile("s_waitcnt vmcnt(8)" ::: "memory");
            } else {
                asm volatile("s_waitcnt vmcnt(0)" ::: "memory");
            }
            ABAR();
            mfmaQ(1, 1, b1);
            ABAR();
        }
    }

    // epilogue: C/D layout col = lane&15, row = (lane>>4)*4 + reg
    #pragma unroll
    for (int i8 = 0; i8 < 8; ++i8) {
        const int qm = i8 >> 2, mf = i8 & 3;
        #pragma unroll
        for (int j4 = 0; j4 < 4; ++j4) {
            const int qn = j4 >> 1, nf = j4 & 1;
            long row = m0 + qm * 128 + wm * 64 + mf * 16 + ((l >> 4) << 2);
            long cb = row * N + n0 + qn * 128 + wn * 32 + nf * 16 + (l & 15);
            if constexpr (OBF16) {
                u16* cp = (u16*)Cv + (long)half * M * N + cb;
                #pragma unroll
                for (int r = 0; r < 4; ++r) cp[(long)r * N] = f2bf(acc[i8][j4][r]);
            } else {
                float* cp = (float*)Cv + cb;
                #pragma unroll
                for (int r = 0; r < 4; ++r) cp[(long)r * N] = acc[i8][j4][r];
            }
        }
    }
}

// ---------------- RoPE + scatter, sums 2 bf16 K-split partials, 4 pairs/thread ------
__global__ void k_rope_scatter(const u16* __restrict__ qkvH, const float* __restrict__ cosb,
                               const float* __restrict__ sinb, u16* __restrict__ Qb,
                               u16* __restrict__ Kb, u16* __restrict__ Vt,
                               float* __restrict__ present)
{
    const long HSTR = 25165824L;   // 4096*6144 elements per half
    long idx = (long)blockIdx.x * 256 + threadIdx.x;   // 0 .. 3,145,727
    int pg   = (int)(idx & 15);
    int rem  = (int)(idx >> 4);
    int slot = rem % 48;
    int tok  = rem / 48;
    int b = tok >> 11, s = tok & 2047;
    int pair = pg * 4;

    const u16* base = qkvH + (long)tok * 6144 + slot * 128 + pair;
    ushort4 p0a = *(const ushort4*)(base);
    ushort4 p0b = *(const ushort4*)(base + 64);
    ushort4 p1a = *(const ushort4*)(base + HSTR);
    ushort4 p1b = *(const ushort4*)(base + HSTR + 64);
    float4 x1 = {b2f(p0a.x) + b2f(p1a.x), b2f(p0a.y) + b2f(p1a.y),
                 b2f(p0a.z) + b2f(p1a.z), b2f(p0a.w) + b2f(p1a.w)};
    float4 x2 = {b2f(p0b.x) + b2f(p1b.x), b2f(p0b.y) + b2f(p1b.y),
                 b2f(p0b.z) + b2f(p1b.z), b2f(p0b.w) + b2f(p1b.w)};

    if (slot < 40) {
        float4 c  = *(const float4*)(cosb + s * 128 + pair);
        float4 sn = *(const float4*)(sinb + s * 128 + pair);
        float4 y1, y2;
        y1.x = x1.x * c.x - x2.x * sn.x;  y2.x = x2.x * c.x + x1.x * sn.x;
        y1.y = x1.y * c.y - x2.y * sn.y;  y2.y = x2.y * c.y + x1.y * sn.y;
        y1.z = x1.z * c.z - x2.z * sn.z;  y2.z = x2.z * c.z + x1.z * sn.z;
        y1.w = x1.w * c.w - x2.w * sn.w;  y2.w = x2.w * c.w + x1.w * sn.w;
        if (slot < 32) {
            const float sc = 0.0883883476483184f;  // 1/sqrt(128), folded into Q
            long qoff = (((long)b * 32 + slot) * 2048 + s) * 128 + pair;
            ushort4 o1, o2;
            o1.x = f2bf(y1.x * sc); o1.y = f2bf(y1.y * sc);
            o1.z = f2bf(y1.z * sc); o1.w = f2bf(y1.w * sc);
            o2.x = f2bf(y2.x * sc); o2.y = f2bf(y2.y * sc);
            o2.z = f2bf(y2.z * sc); o2.w = f2bf(y2.w * sc);
            *(ushort4*)(Qb + qoff)      = o1;
            *(ushort4*)(Qb + qoff + 64) = o2;
        } else {
            int kvh = slot - 32;
            long koff = (((long)b * 8 + kvh) * 2048 + s) * 128 + pair;
            ushort4 o1, o2;
            o1.x = f2bf(y1.x); o1.y = f2bf(y1.y); o1.z = f2bf(y1.z); o1.w = f2bf(y1.w);
            o2.x = f2bf(y2.x); o2.y = f2bf(y2.y); o2.z = f2bf(y2.z); o2.w = f2bf(y2.w);
            *(ushort4*)(Kb + koff)      = o1;
            *(ushort4*)(Kb + koff + 64) = o2;
            long poff = ((((long)b * 2 + 0) * 8 + kvh) * 4096 + s) * 128 + pair;
            *(float4*)(present + poff)      = y1;
            *(float4*)(present + poff + 64) = y2;
        }
    } else {
        int kvh = slot - 40;
        long poff = ((((long)b * 2 + 1) * 8 + kvh) * 4096 + s) * 128 + pair;
        *(float4*)(present + poff)      = x1;
        *(float4*)(present + poff + 64) = x2;
        long voff = (((long)b * 8 + kvh) * 128 + pair) * 2048 + s;
        Vt[voff]             = f2bf(x1.x);
        Vt[voff + 1 * 2048]  = f2bf(x1.y);
        Vt[voff + 2 * 2048]  = f2bf(x1.z);
        Vt[voff + 3 * 2048]  = f2bf(x1.w);
        Vt[voff + 64 * 2048] = f2bf(x2.x);
        Vt[voff + 65 * 2048] = f2bf(x2.y);
        Vt[voff + 66 * 2048] = f2bf(x2.z);
        Vt[voff + 67 * 2048] = f2bf(x2.w);
    }
}

// ---------------- causal GQA flash attention: QBLK=64, 2 waves, 4 blocks/CU ----------
// Pairs (p, 31-p) over 32 q-tiles of 64 rows: (p+1)+(32-p) = 33 K-steps for EVERY
// block -> uniform. Grid 16x32x2 = 1024 blocks = 4 blocks/CU (vs R16's 2): barriers
// span 2 waves instead of 4, and 4 independent blocks/CU give 2x the cross-block
// slack to hide staging latency. Per-wave geometry identical to R8 (32 q-rows/wave).
// LDS 32KB: Ks 16KB (P aliases; 2 waves x 4KB fit) + Vs 16KB.
// (128,2) bounds: cap 256 VGPR, no spill risk (R5 lesson); <=256 VGPR -> 8 waves/CU
// = exactly the 4 blocks x 2 waves we need.
__global__ void __launch_bounds__(128, 2)
k_attn(const u16* __restrict__ Qb, const u16* __restrict__ Kb,
       const u16* __restrict__ Vt, u16* __restrict__ attnB)
{
    __shared__ __align__(16) u16 Ks[64 * 128];   // [key][d] chunk16 swz; P alias after QK
    __shared__ __align__(16) u16 Vs[128 * 64];   // [d][key], chunk8 swz ^(row&7)
    const int l = threadIdx.x & 63;
    const int w = threadIdx.x >> 6;              // 0,1
    const int h = blockIdx.y, b = blockIdx.z;
    const int p = blockIdx.x;                    // 0..15
    const int kvh = h >> 2;
    u16* Psw = &Ks[w * 2048];                    // per-wave 32x64 P, aliases K tile

    const long kbase = ((long)b * 8 + kvh) * (2048L * 128);
    const long vbase = ((long)b * 8 + kvh) * (128L * 2048);
    f32x4 zero = {0.f, 0.f, 0.f, 0.f};

    for (int half = 0; half < 2; ++half) {
        const int qt = half ? (31 - p) : p;      // 0..31, 64-row q-tiles
        const int q0 = qt * 64;

        const long qbase = (((long)b * 32 + h) * 2048 + q0 + w * 32) * 128;
        bf16x8 qf[2][4];
        #pragma unroll
        for (int mi = 0; mi < 2; ++mi)
            #pragma unroll
            for (int kk = 0; kk < 4; ++kk)
                qf[mi][kk] = *(const bf16x8*)(Qb + qbase + (long)(mi * 16 + (l & 15)) * 128
                                              + kk * 32 + ((l >> 4) << 3));

        f32x4 o[2][8];
        float mst[2][4], lst[2][4];
        #pragma unroll
        for (int mi = 0; mi < 2; ++mi) {
            #pragma unroll
            for (int j = 0; j < 8; ++j) o[mi][j] = zero;
            #pragma unroll
            for (int r = 0; r < 4; ++r) { mst[mi][r] = -3.0e38f; lst[mi][r] = 0.f; }
        }

        const int nkt = (q0 >> 6) + 1;  // keys 0 .. q0+63
        for (int kt = 0; kt < nkt; ++kt) {
            const int k0 = kt * 64;
            __syncthreads();  // all waves done with previous tile's Ks(P alias) + Vs
            #pragma unroll
            for (int i = 0; i < 8; ++i) {     // K tile: 16KB, 8 chunks/wave (2 waves)
                int c = w * 8 + i;
                int row = c * 4 + (l >> 4);
                int lg = ((l & 15) ^ (row & 15)) << 3;   // per-i (row&15 varies)
                gl_lds16(Kb + kbase + (long)(k0 + row) * 128 + lg, &Ks[c * 512]);
            }
            #pragma unroll
            for (int i = 0; i < 8; ++i) {     // V^T tile: 16KB, 8 chunks/wave
                int c = w * 8 + i;
                int row = c * 8 + (l >> 3);
                int lg = ((l & 7) ^ (row & 7)) << 3;     // i-invariant (stride 8)
                gl_lds16(Vt + vbase + (long)row * 2048 + k0 + lg, &Vs[c * 512]);
            }
            __syncthreads();  // staging complete

            // ---- S = Q K^T ----
            f32x4 s[2][4];
            #pragma unroll
            for (int mi = 0; mi < 2; ++mi)
                #pragma unroll
                for (int nf = 0; nf < 4; ++nf) s[mi][nf] = zero;
            #pragma unroll
            for (int kk = 0; kk < 4; ++kk) {
                bf16x8 kf[4];
                #pragma unroll
                for (int nf = 0; nf < 4; ++nf) {
                    int row = nf * 16 + (l & 15);
                    int ph = (kk * 4 + (l >> 4)) ^ (row & 15);
                    kf[nf] = *(const bf16x8*)&Ks[row * 128 + ph * 8];
                }
                __builtin_amdgcn_s_setprio(1);
                #pragma unroll
                for (int mi = 0; mi < 2; ++mi)
                    #pragma unroll
                    for (int nf = 0; nf < 4; ++nf)
                        s[mi][nf] = mfma16(qf[mi][kk], kf[nf], s[mi][nf]);
                __builtin_amdgcn_s_setprio(0);
            }
            // ---- causal mask ----
            #pragma unroll
            for (int mi = 0; mi < 2; ++mi)
                #pragma unroll
                for (int nf = 0; nf < 4; ++nf)
                    #pragma unroll
                    for (int r = 0; r < 4; ++r) {
                        int rowg = q0 + w * 32 + mi * 16 + ((l >> 4) << 2) + r;
                        int colg = k0 + nf * 16 + (l & 15);
                        if (colg > rowg) s[mi][nf][r] = -1.0e30f;
                    }
            // ---- online softmax (row reduce over 16-lane group) ----
            #pragma unroll
            for (int mi = 0; mi < 2; ++mi)
                #pragma unroll
                for (int r = 0; r < 4; ++r) {
                    float t = fmaxf(fmaxf(s[mi][0][r], s[mi][1][r]),
                                    fmaxf(s[mi][2][r], s[mi][3][r]));
                    t = fmaxf(t, __shfl_xor(t, 1));
                    t = fmaxf(t, __shfl_xor(t, 2));
                    t = fmaxf(t, __shfl_xor(t, 4));
                    t = fmaxf(t, __shfl_xor(t, 8));
                    float nm = fmaxf(mst[mi][r], t);
                    float sc = __expf(mst[mi][r] - nm);
                    mst[mi][r] = nm;
                    lst[mi][r] *= sc;
                    #pragma unroll
                    for (int nf2 = 0; nf2 < 8; ++nf2) o[mi][nf2][r] *= sc;
                }
            __syncthreads();  // all waves done READING Ks before P overwrites it
            // ---- P = exp(S - m) -> bf16 -> per-wave LDS (aliases Ks) ----
            #pragma unroll
            for (int mi = 0; mi < 2; ++mi)
                #pragma unroll
                for (int nf = 0; nf < 4; ++nf)
                    #pragma unroll
                    for (int r = 0; r < 4; ++r) {
                        float pv = __expf(s[mi][nf][r] - mst[mi][r]);
                        lst[mi][r] += pv;
                        int row = mi * 16 + ((l >> 4) << 2) + r;
                        int col = nf * 16 + (l & 15);
                        Psw[row * 64 + (((col >> 3) ^ (row & 7)) << 3) + (col & 7)] = f2bf(pv);
                    }
            // ---- O += P V ----
            #pragma unroll
            for (int kk2 = 0; kk2 < 2; ++kk2) {
                bf16x8 pa[2];
                #pragma unroll
                for (int mi = 0; mi < 2; ++mi) {
                    int row = mi * 16 + (l & 15);
                    int ph = (kk2 * 4 + (l >> 4)) ^ (row & 7);
                    pa[mi] = *(const bf16x8*)&Psw[row * 64 + ph * 8];
                }
                #pragma unroll
                for (int nf2 = 0; nf2 < 8; ++nf2) {
                    int vrow = nf2 * 16 + (l & 15);
                    int ph = (kk2 * 4 + (l >> 4)) ^ (vrow & 7);
                    bf16x8 vf = *(const bf16x8*)&Vs[vrow * 64 + ph * 8];
                    __builtin_amdgcn_s_setprio(1);
                    #pragma unroll
                    for (int mi = 0; mi < 2; ++mi)
                        o[mi][nf2] = mfma16(pa[mi], vf, o[mi][nf2]);
                    __builtin_amdgcn_s_setprio(0);
                }
            }
        }

        // ---- finalize this q-tile ----
        #pragma unroll
        for (int mi = 0; mi < 2; ++mi)
            #pragma unroll
            for (int r = 0; r < 4; ++r) {
                float t = lst[mi][r];
                t += __shfl_xor(t, 1);
                t += __shfl_xor(t, 2);
                t += __shfl_xor(t, 4);
                t += __shfl_xor(t, 8);
                lst[mi][r] = 1.0f / t;
            }
        #pragma unroll
        for (int mi = 0; mi < 2; ++mi)
            #pragma unroll
            for (int nf2 = 0; nf2 < 8; ++nf2)
                #pragma unroll
                for (int r = 0; r < 4; ++r) {
                    long row = (long)b * 2048 + q0 + w * 32 + mi * 16 + ((l >> 4) << 2) + r;
                    attnB[row * 4096 + h * 128 + nf2 * 16 + (l & 15)] =
                        f2bf(o[mi][nf2][r] * lst[mi][r]);
                }
    }
}

extern "C" void kernel_launch(void* const* d_in, const int* in_sizes, int n_in,
                              void* d_out, int out_size, void* d_ws, size_t ws_size,
                              hipStream_t stream)
{
    (void)in_sizes; (void)n_in; (void)out_size; (void)ws_size;
    const float* hidden = (const float*)d_in[0];
    const float* past   = (const float*)d_in[1];
    const float* cosb   = (const float*)d_in[2];
    const float* sinb   = (const float*)d_in[3];
    const float* Wq     = (const float*)d_in[4];
    const float* Wk     = (const float*)d_in[5];
    const float* Wv     = (const float*)d_in[6];
    const float* Wo     = (const float*)d_in[7];
    float* out     = (float*)d_out;             // (B,S,HID) f32
    float* present = out + 16777216L;           // (B,2,KVH,MAXPOS,D) f32

    // workspace layout (224 MiB total)
    char* ws = (char*)d_ws;
    u16*  hiddenB = (u16*)(ws);                  // 33,554,432 B (later aliased as Qbuf)
    u16*  WqkvT   = (u16*)(ws + 33554432L);      // 50,331,648 B (6144 x 4096 bf16)
    u16*  WoT     = (u16*)(ws + 83886080L);      // 33,554,432 B
    u16*  QKVh    = (u16*)(ws + 117440512L);     // 2 x 50,331,648 B bf16 K-split partials
    u16*  Kb      = (u16*)(ws + 218103808L);     // 8,388,608 B
    u16*  Vt      = (u16*)(ws + 226492416L);     // 8,388,608 B
    u16*  Qbuf    = hiddenB;                     // reuse after QKV GEMM consumed hiddenB
    u16*  attnB   = QKVh;                        // reuse after rope consumed both halves

    static bool attr_done = false;
    if (!attr_done) {
        hipFuncSetAttribute((const void*)k_gemm8ph<1, 2>,
                            hipFuncAttributeMaxDynamicSharedMemorySize, 131072);
        hipFuncSetAttribute((const void*)k_gemm8ph<0, 1>,
                            hipFuncAttributeMaxDynamicSharedMemorySize, 131072);
        attr_done = true;
    }

    k_pre<<<24576, 256, 0, stream>>>(hidden, hiddenB, (const float4*)past, (float4*)present);
    k_transpose_all<<<dim3(320, 128), dim3(32, 8), 0, stream>>>(Wq, Wk, Wv, Wo, WqkvT, WoT);
    // QKV: 8-phase, K-split x2 -> 384 tiles x 2 halves = 768 blocks = 3.0 CU-rounds
    k_gemm8ph<1, 2><<<768, 512, 131072, stream>>>(hiddenB, WqkvT, (void*)QKVh,
                                                  4096, 6144, 4096, 24);
    k_rope_scatter<<<12288, 256, 0, stream>>>(QKVh, cosb, sinb, Qbuf, Kb, Vt, present);
    // attn: QBLK=64 pairs (p,31-p) -> uniform 33 K-steps, 1024 blocks = 4/CU
    k_attn<<<dim3(16, 32, 2), 128, 0, stream>>>(Qbuf, Kb, Vt, attnB);
    // Wo: 8-phase, grid 256 = 1.0 CU-rounds, f32 out
    k_gemm8ph<0, 1><<<256, 512, 131072, stream>>>(attnB, WoT, (void*)out,
                                                  4096, 4096, 4096, 16);
}

// Round 18
// 570.979 us; speedup vs baseline: 1.0325x; 1.0325x over previous
//
#include <hip/hip_runtime.h>
#include <hip/hip_bf16.h>

typedef unsigned short u16;
typedef __bf16 bf16x8 __attribute__((ext_vector_type(8)));
typedef float  f32x4  __attribute__((ext_vector_type(4)));

__device__ __forceinline__ u16 f2bf(float f) {
    return __builtin_bit_cast(u16, (__bf16)f);
}
__device__ __forceinline__ float b2f(u16 u) {
    return __builtin_bit_cast(float, (unsigned)u << 16);
}
__device__ __forceinline__ f32x4 mfma16(bf16x8 a, bf16x8 b, f32x4 c) {
    return __builtin_amdgcn_mfma_f32_16x16x32_bf16(a, b, c, 0, 0, 0);
}
// async global->LDS, 16B per lane; LDS dest is wave-uniform base + lane*16
__device__ __forceinline__ void gl_lds16(const void* g, void* l) {
    __builtin_amdgcn_global_load_lds((const __attribute__((address_space(1))) void*)g,
                                     (__attribute__((address_space(3))) void*)l, 16, 0, 0);
}

// ---------------- fused preprocessing (single launch, 3 block-uniform regions) -------
// bx [0,16384): hidden f32->bf16 cast (4/thread). bx [16384,24576): past-tail copy
// (rows s in [2048,4096) of each (b,k/v,kvh) plane). bx [24576,65536): weight
// transpose+cast Wq/Wk/Wv -> WqkvT, Wo -> WoT (32x32 tiles, LDS-staged).
// All outputs independent; consumed only by later kernels.
__global__ void k_prep(const float* __restrict__ hidden, u16* __restrict__ hiddenB,
                       const float4* __restrict__ past, float4* __restrict__ present4,
                       const float* __restrict__ Wq, const float* __restrict__ Wk,
                       const float* __restrict__ Wv, const float* __restrict__ Wo,
                       u16* __restrict__ WqkvT, u16* __restrict__ WoT) {
    const int bx = blockIdx.x;
    const int t = threadIdx.x;
    if (bx < 16384) {
        long i = ((long)bx * 256 + t) * 4;
        float4 v = *(const float4*)(hidden + i);
        ushort4 o;
        o.x = f2bf(v.x); o.y = f2bf(v.y); o.z = f2bf(v.z); o.w = f2bf(v.w);
        *(ushort4*)(hiddenB + i) = o;
    } else if (bx < 24576) {
        long i = (long)(bx - 16384) * 256 + t;             // 0 .. 2^21-1
        long g = i >> 16;                                  // plane index (32 planes)
        long inner = i & 65535;
        long off = g * 131072 + 65536 + inner;
        present4[off] = past[off];
    } else {
        __shared__ float tile[32][33];
        const int tb = bx - 24576;                         // 0 .. 40959 = 320 x 128
        const int gx = tb % 320;
        const int k0 = (tb / 320) * 32;
        const float* src; u16* dst; int N; int col;
        if (gx < 128)      { src = Wq; N = 4096; col = gx * 32;         dst = WqkvT; }
        else if (gx < 160) { src = Wk; N = 1024; col = (gx - 128) * 32; dst = WqkvT + 4096L * 4096; }
        else if (gx < 192) { src = Wv; N = 1024; col = (gx - 160) * 32; dst = WqkvT + 5120L * 4096; }
        else               { src = Wo; N = 4096; col = (gx - 192) * 32; dst = WoT; }
        const int tx = t & 31, ty = t >> 5;                // 32 x 8
        #pragma unroll
        for (int i = 0; i < 32; i += 8)
            tile[ty + i][tx] = src[(long)(k0 + ty + i) * N + col + tx];
        __syncthreads();
        #pragma unroll
        for (int i = 0; i < 32; i += 8)
            dst[(long)(col + ty + i) * 4096 + k0 + tx] = f2bf(tile[tx][ty + i]);
    }
}

#define ABAR() do { __builtin_amdgcn_sched_barrier(0); __builtin_amdgcn_s_barrier(); \
                    __builtin_amdgcn_sched_barrier(0); } while (0)
#define LGKM0() do { asm volatile("s_waitcnt lgkmcnt(0)" ::: "memory"); \
                     __builtin_amdgcn_sched_barrier(0); } while (0)

// ================= m201-style 8-phase 256x256 GEMM (R15/R16-verified) =================
// C = A(MxK,bf16) * Bt(NxK,bf16)^T. BM=BN=256, BK=64, 512 thr = 8 waves (2M x 4N).
// LDS 128KB = {A,B} x 2dbuf x 2half x [128][64] bf16, chunk16 XOR swizzle.
// Quadrant rotation (0,0),(0,1),(1,0),(1,1); A frags held 2 phases, B held 4.
// vmcnt(8) once per K-tile; counted, never 0 in steady state (T3+T4+T5).
// NSPLIT: K-split; block 'half' covers K range [half*K/NSPLIT, +K/NSPLIT), writes
// bf16 partial to buffer half (consumer sums). QKV: 384 tiles x2 = 768 = 3.0 rounds.
template<int OBF16, int NSPLIT>
__global__ void __launch_bounds__(512, 2)
k_gemm8ph(const u16* __restrict__ A, const u16* __restrict__ Bt,
          void* __restrict__ Cv, int M, int N, int K, int gx)
{
    extern __shared__ u16 lds[];
    const int nwg = gridDim.x;
    const int bid = blockIdx.x;
    const int swzb = (bid & 7) * (nwg >> 3) + (bid >> 3);
    const int tiles = nwg / NSPLIT;
    const int half = swzb / tiles;
    const int tile = swzb % tiles;
    const long m0 = (long)(tile / gx) * 256;
    const long n0 = (long)(tile % gx) * 256;
    const int Klen = K / NSPLIT;
    const long kbase = (long)half * Klen;

    const int t = threadIdx.x;
    const int l = t & 63;
    const int w = t >> 6;
    const int wm = w >> 2, wn = w & 3;

    const int srow = t >> 3;
    const int scol = ((t & 7) ^ (srow & 7)) << 3;   // j-invariant (64 = 0 mod 8)
    const u16* aph[2] = { A  + (m0 + 0   + srow) * (long)K + kbase + scol,
                          A  + (m0 + 128 + srow) * (long)K + kbase + scol };
    const u16* bph[2] = { Bt + (n0 + 0   + srow) * (long)K + kbase + scol,
                          Bt + (n0 + 128 + srow) * (long)K + kbase + scol };

    const int swz0 = (((l >> 4) ^ (l & 7)) << 3);
    const int swz1 = ((((l >> 4) | 4) ^ (l & 7)) << 3);
    const int arowb = (wm * 64 + (l & 15)) * 64;    // + mf*1024
    const int browb = (wn * 32 + (l & 15)) * 64;    // + nf*1024

    f32x4 acc[8][4];
    #pragma unroll
    for (int i = 0; i < 8; ++i)
        #pragma unroll
        for (int j = 0; j < 4; ++j) acc[i][j] = (f32x4){0.f, 0.f, 0.f, 0.f};

    bf16x8 a[4][2], b0[2][2], b1[2][2];

    auto stA = [&](int d, int h, int kt) {
        const u16* s = aph[h] + (long)kt * 64;
        gl_lds16(s,              &lds[(d * 2 + h) * 8192 + t * 8]);
        gl_lds16(s + 64L * K,    &lds[(d * 2 + h) * 8192 + 4096 + t * 8]);
    };
    auto stB = [&](int d, int h, int kt) {
        const u16* s = bph[h] + (long)kt * 64;
        gl_lds16(s,              &lds[32768 + (d * 2 + h) * 8192 + t * 8]);
        gl_lds16(s + 64L * K,    &lds[32768 + (d * 2 + h) * 8192 + 4096 + t * 8]);
    };
    auto rdA = [&](int d, int h) {
        const int base = (d * 2 + h) * 8192;
        #pragma unroll
        for (int mf = 0; mf < 4; ++mf) {
            a[mf][0] = *(const bf16x8*)&lds[base + arowb + mf * 1024 + swz0];
            a[mf][1] = *(const bf16x8*)&lds[base + arowb + mf * 1024 + swz1];
        }
    };
    auto rdB = [&](int d, int h, bf16x8 (&bb)[2][2]) {
        const int base = 32768 + (d * 2 + h) * 8192;
        #pragma unroll
        for (int nf = 0; nf < 2; ++nf) {
            bb[nf][0] = *(const bf16x8*)&lds[base + browb + nf * 1024 + swz0];
            bb[nf][1] = *(const bf16x8*)&lds[base + browb + nf * 1024 + swz1];
        }
    };
    auto mfmaQ = [&](int qm, int qn, bf16x8 (&bb)[2][2]) {
        __builtin_amdgcn_s_setprio(1);
        #pragma unroll
        for (int mf = 0; mf < 4; ++mf)
            #pragma unroll
            for (int nf = 0; nf < 2; ++nf) {
                acc[qm * 4 + mf][qn * 2 + nf] =
                    mfma16(a[mf][0], bb[nf][0], acc[qm * 4 + mf][qn * 2 + nf]);
                acc[qm * 4 + mf][qn * 2 + nf] =
                    mfma16(a[mf][1], bb[nf][1], acc[qm * 4 + mf][qn * 2 + nf]);
            }
        __builtin_amdgcn_s_setprio(0);
        __builtin_amdgcn_sched_barrier(0);
    };

    const int nt = Klen >> 6;   // even (64 or 32)
    stA(0, 0, 0); stB(0, 0, 0); stB(0, 1, 0); stA(0, 1, 0);
    stA(1, 0, 1); stB(1, 0, 1); stB(1, 1, 1); stA(1, 1, 1);
    asm volatile("s_waitcnt vmcnt(8)" ::: "memory");
    __builtin_amdgcn_sched_barrier(0);
    __builtin_amdgcn_s_barrier();
    __builtin_amdgcn_sched_barrier(0);

    for (int kt = 0; kt < nt; kt += 2) {
        const bool g = (kt + 2) < nt;
        #pragma unroll
        for (int hh = 0; hh < 2; ++hh) {      // hh=0: dbuf0/tile kt; hh=1: dbuf1/kt+1
            const int d = hh;
            const int ktp = kt + 2 + hh;      // stage target tile
            // ---- phase 1: quadrant (0,0) ----
            rdA(d, 0); rdB(d, 0, b0);
            ABAR(); LGKM0();
            mfmaQ(0, 0, b0);
            ABAR();
            // ---- phase 2: quadrant (0,1); stage (ktp).A0,B0 ----
            rdB(d, 1, b1);
            if (g) { stA(d, 0, ktp); stB(d, 0, ktp); }
            ABAR(); LGKM0();
            mfmaQ(0, 1, b1);
            ABAR();
            // ---- phase 3: quadrant (1,0); stage (ktp).B1 ----
            rdA(d, 1);
            if (g) stB(d, 1, ktp);
            ABAR(); LGKM0();
            mfmaQ(1, 0, b0);
            ABAR();
            // ---- phase 4: quadrant (1,1); stage (ktp).A1; vmcnt(8) ----
            if (g) {
                stA(d, 1, ktp);
                asm volatile("s_waitcnt vmcnt(8)" ::: "memory");
            } else {
                asm volatile("s_waitcnt vmcnt(0)" ::: "memory");
            }
            ABAR();
            mfmaQ(1, 1, b1);
            ABAR();
        }
    }

    // epilogue: C/D layout col = lane&15, row = (lane>>4)*4 + reg
    #pragma unroll
    for (int i8 = 0; i8 < 8; ++i8) {
        const int qm = i8 >> 2, mf = i8 & 3;
        #pragma unroll
        for (int j4 = 0; j4 < 4; ++j4) {
            const int qn = j4 >> 1, nf = j4 & 1;
            long row = m0 + qm * 128 + wm * 64 + mf * 16 + ((l >> 4) << 2);
            long cb = row * N + n0 + qn * 128 + wn * 32 + nf * 16 + (l & 15);
            if constexpr (OBF16) {
                u16* cp = (u16*)Cv + (long)half * M * N + cb;
                #pragma unroll
                for (int r = 0; r < 4; ++r) cp[(long)r * N] = f2bf(acc[i8][j4][r]);
            } else {
                float* cp = (float*)Cv + cb;
                #pragma unroll
                for (int r = 0; r < 4; ++r) cp[(long)r * N] = acc[i8][j4][r];
            }
        }
    }
}

// ---------------- RoPE + scatter, sums 2 bf16 K-split partials, 4 pairs/thread ------
__global__ void k_rope_scatter(const u16* __restrict__ qkvH, const float* __restrict__ cosb,
                               const float* __restrict__ sinb, u16* __restrict__ Qb,
                               u16* __restrict__ Kb, u16* __restrict__ Vt,
                               float* __restrict__ present)
{
    const long HSTR = 25165824L;   // 4096*6144 elements per half
    long idx = (long)blockIdx.x * 256 + threadIdx.x;   // 0 .. 3,145,727
    int pg   = (int)(idx & 15);
    int rem  = (int)(idx >> 4);
    int slot = rem % 48;
    int tok  = rem / 48;
    int b = tok >> 11, s = tok & 2047;
    int pair = pg * 4;

    const u16* base = qkvH + (long)tok * 6144 + slot * 128 + pair;
    ushort4 p0a = *(const ushort4*)(base);
    ushort4 p0b = *(const ushort4*)(base + 64);
    ushort4 p1a = *(const ushort4*)(base + HSTR);
    ushort4 p1b = *(const ushort4*)(base + HSTR + 64);
    float4 x1 = {b2f(p0a.x) + b2f(p1a.x), b2f(p0a.y) + b2f(p1a.y),
                 b2f(p0a.z) + b2f(p1a.z), b2f(p0a.w) + b2f(p1a.w)};
    float4 x2 = {b2f(p0b.x) + b2f(p1b.x), b2f(p0b.y) + b2f(p1b.y),
                 b2f(p0b.z) + b2f(p1b.z), b2f(p0b.w) + b2f(p1b.w)};

    if (slot < 40) {
        float4 c  = *(const float4*)(cosb + s * 128 + pair);
        float4 sn = *(const float4*)(sinb + s * 128 + pair);
        float4 y1, y2;
        y1.x = x1.x * c.x - x2.x * sn.x;  y2.x = x2.x * c.x + x1.x * sn.x;
        y1.y = x1.y * c.y - x2.y * sn.y;  y2.y = x2.y * c.y + x1.y * sn.y;
        y1.z = x1.z * c.z - x2.z * sn.z;  y2.z = x2.z * c.z + x1.z * sn.z;
        y1.w = x1.w * c.w - x2.w * sn.w;  y2.w = x2.w * c.w + x1.w * sn.w;
        if (slot < 32) {
            const float sc = 0.0883883476483184f;  // 1/sqrt(128), folded into Q
            long qoff = (((long)b * 32 + slot) * 2048 + s) * 128 + pair;
            ushort4 o1, o2;
            o1.x = f2bf(y1.x * sc); o1.y = f2bf(y1.y * sc);
            o1.z = f2bf(y1.z * sc); o1.w = f2bf(y1.w * sc);
            o2.x = f2bf(y2.x * sc); o2.y = f2bf(y2.y * sc);
            o2.z = f2bf(y2.z * sc); o2.w = f2bf(y2.w * sc);
            *(ushort4*)(Qb + qoff)      = o1;
            *(ushort4*)(Qb + qoff + 64) = o2;
        } else {
            int kvh = slot - 32;
            long koff = (((long)b * 8 + kvh) * 2048 + s) * 128 + pair;
            ushort4 o1, o2;
            o1.x = f2bf(y1.x); o1.y = f2bf(y1.y); o1.z = f2bf(y1.z); o1.w = f2bf(y1.w);
            o2.x = f2bf(y2.x); o2.y = f2bf(y2.y); o2.z = f2bf(y2.z); o2.w = f2bf(y2.w);
            *(ushort4*)(Kb + koff)      = o1;
            *(ushort4*)(Kb + koff + 64) = o2;
            long poff = ((((long)b * 2 + 0) * 8 + kvh) * 4096 + s) * 128 + pair;
            *(float4*)(present + poff)      = y1;
            *(float4*)(present + poff + 64) = y2;
        }
    } else {
        int kvh = slot - 40;
        long poff = ((((long)b * 2 + 1) * 8 + kvh) * 4096 + s) * 128 + pair;
        *(float4*)(present + poff)      = x1;
        *(float4*)(present + poff + 64) = x2;
        long voff = (((long)b * 8 + kvh) * 128 + pair) * 2048 + s;
        Vt[voff]             = f2bf(x1.x);
        Vt[voff + 1 * 2048]  = f2bf(x1.y);
        Vt[voff + 2 * 2048]  = f2bf(x1.z);
        Vt[voff + 3 * 2048]  = f2bf(x1.w);
        Vt[voff + 64 * 2048] = f2bf(x2.x);
        Vt[voff + 65 * 2048] = f2bf(x2.y);
        Vt[voff + 66 * 2048] = f2bf(x2.z);
        Vt[voff + 67 * 2048] = f2bf(x2.w);
    }
}

// ---------------- causal GQA flash attention (R16-proven: QBLK=128, 4 waves) ---------
// Uniform-work paired q-tiles: block p handles qt=p and qt=15-p -> 34 K-steps every
// block. 512 blocks = 2/CU, 4 waves each. LDS 32KB: Ks (16KB, P aliases after QK^T)
// + Vs (16KB) -> 4 blocks/CU limit is VGPR-bound at 2 in practice; this config beat
// both the 80KB dbuf variant (R11, -30us) and the QBLK=64 2-wave variant (R17, -14us:
// halving QBLK doubles total K/V staging volume). launch_bounds must stay (256,2).
__global__ void __launch_bounds__(256, 2)
k_attn(const u16* __restrict__ Qb, const u16* __restrict__ Kb,
       const u16* __restrict__ Vt, u16* __restrict__ attnB)
{
    __shared__ __align__(16) u16 Ks[64 * 128];   // [key][d] chunk16 swz; P alias after QK
    __shared__ __align__(16) u16 Vs[128 * 64];   // [d][key], chunk8 swz ^(row&7)
    const int l = threadIdx.x & 63;
    const int w = threadIdx.x >> 6;
    const int h = blockIdx.y, b = blockIdx.z;
    const int p = blockIdx.x;
    const int kvh = h >> 2;
    u16* Psw = &Ks[w * 2048];                    // per-wave 32x64 P, aliases K tile

    const long kbase = ((long)b * 8 + kvh) * (2048L * 128);
    const long vbase = ((long)b * 8 + kvh) * (128L * 2048);
    f32x4 zero = {0.f, 0.f, 0.f, 0.f};

    for (int half = 0; half < 2; ++half) {
        const int qt = half ? (15 - p) : p;
        const int q0 = qt * 128;

        const long qbase = (((long)b * 32 + h) * 2048 + q0 + w * 32) * 128;
        bf16x8 qf[2][4];
        #pragma unroll
        for (int mi = 0; mi < 2; ++mi)
            #pragma unroll
            for (int kk = 0; kk < 4; ++kk)
                qf[mi][kk] = *(const bf16x8*)(Qb + qbase + (long)(mi * 16 + (l & 15)) * 128
                                              + kk * 32 + ((l >> 4) << 3));

        f32x4 o[2][8];
        float mst[2][4], lst[2][4];
        #pragma unroll
        for (int mi = 0; mi < 2; ++mi) {
            #pragma unroll
            for (int j = 0; j < 8; ++j) o[mi][j] = zero;
            #pragma unroll
            for (int r = 0; r < 4; ++r) { mst[mi][r] = -3.0e38f; lst[mi][r] = 0.f; }
        }

        const int nkt = (q0 >> 6) + 2;  // keys 0 .. q0+127
        for (int kt = 0; kt < nkt; ++kt) {
            const int k0 = kt * 64;
            __syncthreads();
            #pragma unroll
            for (int i = 0; i < 4; ++i) {     // K tile: 16KB, 4 chunks/wave
                int c = w * 4 + i;
                int row = c * 4 + (l >> 4);
                int lg = ((l & 15) ^ (row & 15)) << 3;
                gl_lds16(Kb + kbase + (long)(k0 + row) * 128 + lg, &Ks[c * 512]);
            }
            #pragma unroll
            for (int i = 0; i < 4; ++i) {     // V^T tile: 16KB
                int c = w * 4 + i;
                int row = c * 8 + (l >> 3);
                int lg = ((l & 7) ^ (row & 7)) << 3;
                gl_lds16(Vt + vbase + (long)row * 2048 + k0 + lg, &Vs[c * 512]);
            }
            __syncthreads();

            f32x4 s[2][4];
            #pragma unroll
            for (int mi = 0; mi < 2; ++mi)
                #pragma unroll
                for (int nf = 0; nf < 4; ++nf) s[mi][nf] = zero;
            #pragma unroll
            for (int kk = 0; kk < 4; ++kk) {
                bf16x8 kf[4];
                #pragma unroll
                for (int nf = 0; nf < 4; ++nf) {
                    int row = nf * 16 + (l & 15);
                    int ph = (kk * 4 + (l >> 4)) ^ (row & 15);
                    kf[nf] = *(const bf16x8*)&Ks[row * 128 + ph * 8];
                }
                __builtin_amdgcn_s_setprio(1);
                #pragma unroll
                for (int mi = 0; mi < 2; ++mi)
                    #pragma unroll
                    for (int nf = 0; nf < 4; ++nf)
                        s[mi][nf] = mfma16(qf[mi][kk], kf[nf], s[mi][nf]);
                __builtin_amdgcn_s_setprio(0);
            }
            #pragma unroll
            for (int mi = 0; mi < 2; ++mi)
                #pragma unroll
                for (int nf = 0; nf < 4; ++nf)
                    #pragma unroll
                    for (int r = 0; r < 4; ++r) {
                        int rowg = q0 + w * 32 + mi * 16 + ((l >> 4) << 2) + r;
                        int colg = k0 + nf * 16 + (l & 15);
                        if (colg > rowg) s[mi][nf][r] = -1.0e30f;
                    }
            #pragma unroll
            for (int mi = 0; mi < 2; ++mi)
                #pragma unroll
                for (int r = 0; r < 4; ++r) {
                    float t = fmaxf(fmaxf(s[mi][0][r], s[mi][1][r]),
                                    fmaxf(s[mi][2][r], s[mi][3][r]));
                    t = fmaxf(t, __shfl_xor(t, 1));
                    t = fmaxf(t, __shfl_xor(t, 2));
                    t = fmaxf(t, __shfl_xor(t, 4));
                    t = fmaxf(t, __shfl_xor(t, 8));
                    float nm = fmaxf(mst[mi][r], t);
                    float sc = __expf(mst[mi][r] - nm);
                    mst[mi][r] = nm;
                    lst[mi][r] *= sc;
                    #pragma unroll
                    for (int nf2 = 0; nf2 < 8; ++nf2) o[mi][nf2][r] *= sc;
                }
            __syncthreads();  // all waves done READING Ks before P overwrites it
            #pragma unroll
            for (int mi = 0; mi < 2; ++mi)
                #pragma unroll
                for (int nf = 0; nf < 4; ++nf)
                    #pragma unroll
                    for (int r = 0; r < 4; ++r) {
                        float pv = __expf(s[mi][nf][r] - mst[mi][r]);
                        lst[mi][r] += pv;
                        int row = mi * 16 + ((l >> 4) << 2) + r;
                        int col = nf * 16 + (l & 15);
                        Psw[row * 64 + (((col >> 3) ^ (row & 7)) << 3) + (col & 7)] = f2bf(pv);
                    }
            #pragma unroll
            for (int kk2 = 0; kk2 < 2; ++kk2) {
                bf16x8 pa[2];
                #pragma unroll
                for (int mi = 0; mi < 2; ++mi) {
                    int row = mi * 16 + (l & 15);
                    int ph = (kk2 * 4 + (l >> 4)) ^ (row & 7);
                    pa[mi] = *(const bf16x8*)&Psw[row * 64 + ph * 8];
                }
                #pragma unroll
                for (int nf2 = 0; nf2 < 8; ++nf2) {
                    int vrow = nf2 * 16 + (l & 15);
                    int ph = (kk2 * 4 + (l >> 4)) ^ (vrow & 7);
                    bf16x8 vf = *(const bf16x8*)&Vs[vrow * 64 + ph * 8];
                    __builtin_amdgcn_s_setprio(1);
                    #pragma unroll
                    for (int mi = 0; mi < 2; ++mi)
                        o[mi][nf2] = mfma16(pa[mi], vf, o[mi][nf2]);
                    __builtin_amdgcn_s_setprio(0);
                }
            }
        }

        #pragma unroll
        for (int mi = 0; mi < 2; ++mi)
            #pragma unroll
            for (int r = 0; r < 4; ++r) {
                float t = lst[mi][r];
                t += __shfl_xor(t, 1);
                t += __shfl_xor(t, 2);
                t += __shfl_xor(t, 4);
                t += __shfl_xor(t, 8);
                lst[mi][r] = 1.0f / t;
            }
        #pragma unroll
        for (int mi = 0; mi < 2; ++mi)
            #pragma unroll
            for (int nf2 = 0; nf2 < 8; ++nf2)
                #pragma unroll
                for (int r = 0; r < 4; ++r) {
                    long row = (long)b * 2048 + q0 + w * 32 + mi * 16 + ((l >> 4) << 2) + r;
                    attnB[row * 4096 + h * 128 + nf2 * 16 + (l & 15)] =
                        f2bf(o[mi][nf2][r] * lst[mi][r]);
                }
    }
}

extern "C" void kernel_launch(void* const* d_in, const int* in_sizes, int n_in,
                              void* d_out, int out_size, void* d_ws, size_t ws_size,
                              hipStream_t stream)
{
    (void)in_sizes; (void)n_in; (void)out_size; (void)ws_size;
    const float* hidden = (const float*)d_in[0];
    const float* past   = (const float*)d_in[1];
    const float* cosb   = (const float*)d_in[2];
    const float* sinb   = (const float*)d_in[3];
    const float* Wq     = (const float*)d_in[4];
    const float* Wk     = (const float*)d_in[5];
    const float* Wv     = (const float*)d_in[6];
    const float* Wo     = (const float*)d_in[7];
    float* out     = (float*)d_out;             // (B,S,HID) f32
    float* present = out + 16777216L;           // (B,2,KVH,MAXPOS,D) f32

    // workspace layout (224 MiB total)
    char* ws = (char*)d_ws;
    u16*  hiddenB = (u16*)(ws);                  // 33,554,432 B (later aliased as Qbuf)
    u16*  WqkvT   = (u16*)(ws + 33554432L);      // 50,331,648 B (6144 x 4096 bf16)
    u16*  WoT     = (u16*)(ws + 83886080L);      // 33,554,432 B
    u16*  QKVh    = (u16*)(ws + 117440512L);     // 2 x 50,331,648 B bf16 K-split partials
    u16*  Kb      = (u16*)(ws + 218103808L);     // 8,388,608 B
    u16*  Vt      = (u16*)(ws + 226492416L);     // 8,388,608 B
    u16*  Qbuf    = hiddenB;                     // reuse after QKV GEMM consumed hiddenB
    u16*  attnB   = QKVh;                        // reuse after rope consumed both halves

    static bool attr_done = false;
    if (!attr_done) {
        hipFuncSetAttribute((const void*)k_gemm8ph<1, 2>,
                            hipFuncAttributeMaxDynamicSharedMemorySize, 131072);
        hipFuncSetAttribute((const void*)k_gemm8ph<0, 1>,
                            hipFuncAttributeMaxDynamicSharedMemorySize, 131072);
        attr_done = true;
    }

    // fused prep: cast (16384) + past-tail copy (8192) + weight transposes (40960)
    k_prep<<<65536, 256, 0, stream>>>(hidden, hiddenB, (const float4*)past,
                                      (float4*)present, Wq, Wk, Wv, Wo, WqkvT, WoT);
    // QKV: 8-phase, K-split x2 -> 384 tiles x 2 halves = 768 blocks = 3.0 CU-rounds
    k_gemm8ph<1, 2><<<768, 512, 131072, stream>>>(hiddenB, WqkvT, (void*)QKVh,
                                                  4096, 6144, 4096, 24);
    k_rope_scatter<<<12288, 256, 0, stream>>>(QKVh, cosb, sinb, Qbuf, Kb, Vt, present);
    // attn: paired q-tiles (p, 15-p) -> uniform 34 K-steps/block, 512 blocks
    k_attn<<<dim3(8, 32, 2), 256, 0, stream>>>(Qbuf, Kb, Vt, attnB);
    // Wo: 8-phase, grid 256 = 1.0 CU-rounds, f32 out
    k_gemm8ph<0, 1><<<256, 512, 131072, stream>>>(attnB, WoT, (void*)out,
                                                  4096, 4096, 4096, 16);
}

// Round 19
// 561.241 us; speedup vs baseline: 1.0504x; 1.0174x over previous
//
#include <hip/hip_runtime.h>
#include <hip/hip_bf16.h>

typedef unsigned short u16;
typedef __bf16 bf16x8 __attribute__((ext_vector_type(8)));
typedef float  f32x4  __attribute__((ext_vector_type(4)));

__device__ __forceinline__ u16 f2bf(float f) {
    return __builtin_bit_cast(u16, (__bf16)f);
}
__device__ __forceinline__ float b2f(u16 u) {
    return __builtin_bit_cast(float, (unsigned)u << 16);
}
__device__ __forceinline__ f32x4 mfma16(bf16x8 a, bf16x8 b, f32x4 c) {
    return __builtin_amdgcn_mfma_f32_16x16x32_bf16(a, b, c, 0, 0, 0);
}
// async global->LDS, 16B per lane; LDS dest is wave-uniform base + lane*16
__device__ __forceinline__ void gl_lds16(const void* g, void* l) {
    __builtin_amdgcn_global_load_lds((const __attribute__((address_space(1))) void*)g,
                                     (__attribute__((address_space(3))) void*)l, 16, 0, 0);
}

// ---------------- fused preprocessing (single launch, 3 block-uniform regions) -------
__global__ void k_prep(const float* __restrict__ hidden, u16* __restrict__ hiddenB,
                       const float4* __restrict__ past, float4* __restrict__ present4,
                       const float* __restrict__ Wq, const float* __restrict__ Wk,
                       const float* __restrict__ Wv, const float* __restrict__ Wo,
                       u16* __restrict__ WqkvT, u16* __restrict__ WoT) {
    const int bx = blockIdx.x;
    const int t = threadIdx.x;
    if (bx < 16384) {
        long i = ((long)bx * 256 + t) * 4;
        float4 v = *(const float4*)(hidden + i);
        ushort4 o;
        o.x = f2bf(v.x); o.y = f2bf(v.y); o.z = f2bf(v.z); o.w = f2bf(v.w);
        *(ushort4*)(hiddenB + i) = o;
    } else if (bx < 24576) {
        long i = (long)(bx - 16384) * 256 + t;             // 0 .. 2^21-1
        long g = i >> 16;                                  // plane index (32 planes)
        long inner = i & 65535;
        long off = g * 131072 + 65536 + inner;
        present4[off] = past[off];
    } else {
        __shared__ float tile[32][33];
        const int tb = bx - 24576;                         // 0 .. 40959 = 320 x 128
        const int gx = tb % 320;
        const int k0 = (tb / 320) * 32;
        const float* src; u16* dst; int N; int col;
        if (gx < 128)      { src = Wq; N = 4096; col = gx * 32;         dst = WqkvT; }
        else if (gx < 160) { src = Wk; N = 1024; col = (gx - 128) * 32; dst = WqkvT + 4096L * 4096; }
        else if (gx < 192) { src = Wv; N = 1024; col = (gx - 160) * 32; dst = WqkvT + 5120L * 4096; }
        else               { src = Wo; N = 4096; col = (gx - 192) * 32; dst = WoT; }
        const int tx = t & 31, ty = t >> 5;                // 32 x 8
        #pragma unroll
        for (int i = 0; i < 32; i += 8)
            tile[ty + i][tx] = src[(long)(k0 + ty + i) * N + col + tx];
        __syncthreads();
        #pragma unroll
        for (int i = 0; i < 32; i += 8)
            dst[(long)(col + ty + i) * 4096 + k0 + tx] = f2bf(tile[tx][ty + i]);
    }
}

#define ABAR() do { __builtin_amdgcn_sched_barrier(0); __builtin_amdgcn_s_barrier(); \
                    __builtin_amdgcn_sched_barrier(0); } while (0)
#define LGKM0() do { asm volatile("s_waitcnt lgkmcnt(0)" ::: "memory"); \
                     __builtin_amdgcn_sched_barrier(0); } while (0)

// ================= m201-style 8-phase 256x256 GEMM (R15/R16-verified) =================
// C = A(MxK,bf16) * Bt(NxK,bf16)^T. BM=BN=256, BK=64, 512 thr = 8 waves (2M x 4N).
// LDS 128KB = {A,B} x 2dbuf x 2half x [128][64] bf16, chunk16 XOR swizzle.
// Quadrant rotation (0,0),(0,1),(1,0),(1,1); A frags held 2 phases, B held 4.
// vmcnt(8) once per K-tile; counted, never 0 in steady state (T3+T4+T5).
// NSPLIT: K-split; block 'half' covers K range [half*K/NSPLIT, +K/NSPLIT), writes
// bf16 partial to buffer half (consumer sums). QKV: 384 tiles x2 = 768 = 3.0 rounds.
// Session ceiling note: 42% MfmaUtil; per-tile elapsed ~1475cyc vs 620 MFMA +
// 770 LDS-read — remaining gap is instruction-level interleave (m201's last 20%);
// blind schedule edits R7/R9 nulled, R15 captured +6pts. Frozen here.
template<int OBF16, int NSPLIT>
__global__ void __launch_bounds__(512, 2)
k_gemm8ph(const u16* __restrict__ A, const u16* __restrict__ Bt,
          void* __restrict__ Cv, int M, int N, int K, int gx)
{
    extern __shared__ u16 lds[];
    const int nwg = gridDim.x;
    const int bid = blockIdx.x;
    const int swzb = (bid & 7) * (nwg >> 3) + (bid >> 3);
    const int tiles = nwg / NSPLIT;
    const int half = swzb / tiles;
    const int tile = swzb % tiles;
    const long m0 = (long)(tile / gx) * 256;
    const long n0 = (long)(tile % gx) * 256;
    const int Klen = K / NSPLIT;
    const long kbase = (long)half * Klen;

    const int t = threadIdx.x;
    const int l = t & 63;
    const int w = t >> 6;
    const int wm = w >> 2, wn = w & 3;

    const int srow = t >> 3;
    const int scol = ((t & 7) ^ (srow & 7)) << 3;   // j-invariant (64 = 0 mod 8)
    const u16* aph[2] = { A  + (m0 + 0   + srow) * (long)K + kbase + scol,
                          A  + (m0 + 128 + srow) * (long)K + kbase + scol };
    const u16* bph[2] = { Bt + (n0 + 0   + srow) * (long)K + kbase + scol,
                          Bt + (n0 + 128 + srow) * (long)K + kbase + scol };

    const int swz0 = (((l >> 4) ^ (l & 7)) << 3);
    const int swz1 = ((((l >> 4) | 4) ^ (l & 7)) << 3);
    const int arowb = (wm * 64 + (l & 15)) * 64;    // + mf*1024
    const int browb = (wn * 32 + (l & 15)) * 64;    // + nf*1024

    f32x4 acc[8][4];
    #pragma unroll
    for (int i = 0; i < 8; ++i)
        #pragma unroll
        for (int j = 0; j < 4; ++j) acc[i][j] = (f32x4){0.f, 0.f, 0.f, 0.f};

    bf16x8 a[4][2], b0[2][2], b1[2][2];

    auto stA = [&](int d, int h, int kt) {
        const u16* s = aph[h] + (long)kt * 64;
        gl_lds16(s,              &lds[(d * 2 + h) * 8192 + t * 8]);
        gl_lds16(s + 64L * K,    &lds[(d * 2 + h) * 8192 + 4096 + t * 8]);
    };
    auto stB = [&](int d, int h, int kt) {
        const u16* s = bph[h] + (long)kt * 64;
        gl_lds16(s,              &lds[32768 + (d * 2 + h) * 8192 + t * 8]);
        gl_lds16(s + 64L * K,    &lds[32768 + (d * 2 + h) * 8192 + 4096 + t * 8]);
    };
    auto rdA = [&](int d, int h) {
        const int base = (d * 2 + h) * 8192;
        #pragma unroll
        for (int mf = 0; mf < 4; ++mf) {
            a[mf][0] = *(const bf16x8*)&lds[base + arowb + mf * 1024 + swz0];
            a[mf][1] = *(const bf16x8*)&lds[base + arowb + mf * 1024 + swz1];
        }
    };
    auto rdB = [&](int d, int h, bf16x8 (&bb)[2][2]) {
        const int base = 32768 + (d * 2 + h) * 8192;
        #pragma unroll
        for (int nf = 0; nf < 2; ++nf) {
            bb[nf][0] = *(const bf16x8*)&lds[base + browb + nf * 1024 + swz0];
            bb[nf][1] = *(const bf16x8*)&lds[base + browb + nf * 1024 + swz1];
        }
    };
    auto mfmaQ = [&](int qm, int qn, bf16x8 (&bb)[2][2]) {
        __builtin_amdgcn_s_setprio(1);
        #pragma unroll
        for (int mf = 0; mf < 4; ++mf)
            #pragma unroll
            for (int nf = 0; nf < 2; ++nf) {
                acc[qm * 4 + mf][qn * 2 + nf] =
                    mfma16(a[mf][0], bb[nf][0], acc[qm * 4 + mf][qn * 2 + nf]);
                acc[qm * 4 + mf][qn * 2 + nf] =
                    mfma16(a[mf][1], bb[nf][1], acc[qm * 4 + mf][qn * 2 + nf]);
            }
        __builtin_amdgcn_s_setprio(0);
        __builtin_amdgcn_sched_barrier(0);
    };

    const int nt = Klen >> 6;   // even (64 or 32)
    stA(0, 0, 0); stB(0, 0, 0); stB(0, 1, 0); stA(0, 1, 0);
    stA(1, 0, 1); stB(1, 0, 1); stB(1, 1, 1); stA(1, 1, 1);
    asm volatile("s_waitcnt vmcnt(8)" ::: "memory");
    __builtin_amdgcn_sched_barrier(0);
    __builtin_amdgcn_s_barrier();
    __builtin_amdgcn_sched_barrier(0);

    for (int kt = 0; kt < nt; kt += 2) {
        const bool g = (kt + 2) < nt;
        #pragma unroll
        for (int hh = 0; hh < 2; ++hh) {      // hh=0: dbuf0/tile kt; hh=1: dbuf1/kt+1
            const int d = hh;
            const int ktp = kt + 2 + hh;      // stage target tile
            // ---- phase 1: quadrant (0,0) ----
            rdA(d, 0); rdB(d, 0, b0);
            ABAR(); LGKM0();
            mfmaQ(0, 0, b0);
            ABAR();
            // ---- phase 2: quadrant (0,1); stage (ktp).A0,B0 ----
            rdB(d, 1, b1);
            if (g) { stA(d, 0, ktp); stB(d, 0, ktp); }
            ABAR(); LGKM0();
            mfmaQ(0, 1, b1);
            ABAR();
            // ---- phase 3: quadrant (1,0); stage (ktp).B1 ----
            rdA(d, 1);
            if (g) stB(d, 1, ktp);
            ABAR(); LGKM0();
            mfmaQ(1, 0, b0);
            ABAR();
            // ---- phase 4: quadrant (1,1); stage (ktp).A1; vmcnt(8) ----
            if (g) {
                stA(d, 1, ktp);
                asm volatile("s_waitcnt vmcnt(8)" ::: "memory");
            } else {
                asm volatile("s_waitcnt vmcnt(0)" ::: "memory");
            }
            ABAR();
            mfmaQ(1, 1, b1);
            ABAR();
        }
    }

    // epilogue: C/D layout col = lane&15, row = (lane>>4)*4 + reg
    #pragma unroll
    for (int i8 = 0; i8 < 8; ++i8) {
        const int qm = i8 >> 2, mf = i8 & 3;
        #pragma unroll
        for (int j4 = 0; j4 < 4; ++j4) {
            const int qn = j4 >> 1, nf = j4 & 1;
            long row = m0 + qm * 128 + wm * 64 + mf * 16 + ((l >> 4) << 2);
            long cb = row * N + n0 + qn * 128 + wn * 32 + nf * 16 + (l & 15);
            if constexpr (OBF16) {
                u16* cp = (u16*)Cv + (long)half * M * N + cb;
                #pragma unroll
                for (int r = 0; r < 4; ++r) cp[(long)r * N] = f2bf(acc[i8][j4][r]);
            } else {
                float* cp = (float*)Cv + cb;
                #pragma unroll
                for (int r = 0; r < 4; ++r) cp[(long)r * N] = acc[i8][j4][r];
            }
        }
    }
}

// ---------------- RoPE + scatter, sums 2 bf16 K-split partials, 4 pairs/thread ------
__global__ void k_rope_scatter(const u16* __restrict__ qkvH, const float* __restrict__ cosb,
                               const float* __restrict__ sinb, u16* __restrict__ Qb,
                               u16* __restrict__ Kb, u16* __restrict__ Vt,
                               float* __restrict__ present)
{
    const long HSTR = 25165824L;   // 4096*6144 elements per half
    long idx = (long)blockIdx.x * 256 + threadIdx.x;   // 0 .. 3,145,727
    int pg   = (int)(idx & 15);
    int rem  = (int)(idx >> 4);
    int slot = rem % 48;
    int tok  = rem / 48;
    int b = tok >> 11, s = tok & 2047;
    int pair = pg * 4;

    const u16* base = qkvH + (long)tok * 6144 + slot * 128 + pair;
    ushort4 p0a = *(const ushort4*)(base);
    ushort4 p0b = *(const ushort4*)(base + 64);
    ushort4 p1a = *(const ushort4*)(base + HSTR);
    ushort4 p1b = *(const ushort4*)(base + HSTR + 64);
    float4 x1 = {b2f(p0a.x) + b2f(p1a.x), b2f(p0a.y) + b2f(p1a.y),
                 b2f(p0a.z) + b2f(p1a.z), b2f(p0a.w) + b2f(p1a.w)};
    float4 x2 = {b2f(p0b.x) + b2f(p1b.x), b2f(p0b.y) + b2f(p1b.y),
                 b2f(p0b.z) + b2f(p1b.z), b2f(p0b.w) + b2f(p1b.w)};

    if (slot < 40) {
        float4 c  = *(const float4*)(cosb + s * 128 + pair);
        float4 sn = *(const float4*)(sinb + s * 128 + pair);
        float4 y1, y2;
        y1.x = x1.x * c.x - x2.x * sn.x;  y2.x = x2.x * c.x + x1.x * sn.x;
        y1.y = x1.y * c.y - x2.y * sn.y;  y2.y = x2.y * c.y + x1.y * sn.y;
        y1.z = x1.z * c.z - x2.z * sn.z;  y2.z = x2.z * c.z + x1.z * sn.z;
        y1.w = x1.w * c.w - x2.w * sn.w;  y2.w = x2.w * c.w + x1.w * sn.w;
        if (slot < 32) {
            const float sc = 0.0883883476483184f;  // 1/sqrt(128), folded into Q
            long qoff = (((long)b * 32 + slot) * 2048 + s) * 128 + pair;
            ushort4 o1, o2;
            o1.x = f2bf(y1.x * sc); o1.y = f2bf(y1.y * sc);
            o1.z = f2bf(y1.z * sc); o1.w = f2bf(y1.w * sc);
            o2.x = f2bf(y2.x * sc); o2.y = f2bf(y2.y * sc);
            o2.z = f2bf(y2.z * sc); o2.w = f2bf(y2.w * sc);
            *(ushort4*)(Qb + qoff)      = o1;
            *(ushort4*)(Qb + qoff + 64) = o2;
        } else {
            int kvh = slot - 32;
            long koff = (((long)b * 8 + kvh) * 2048 + s) * 128 + pair;
            ushort4 o1, o2;
            o1.x = f2bf(y1.x); o1.y = f2bf(y1.y); o1.z = f2bf(y1.z); o1.w = f2bf(y1.w);
            o2.x = f2bf(y2.x); o2.y = f2bf(y2.y); o2.z = f2bf(y2.z); o2.w = f2bf(y2.w);
            *(ushort4*)(Kb + koff)      = o1;
            *(ushort4*)(Kb + koff + 64) = o2;
            long poff = ((((long)b * 2 + 0) * 8 + kvh) * 4096 + s) * 128 + pair;
            *(float4*)(present + poff)      = y1;
            *(float4*)(present + poff + 64) = y2;
        }
    } else {
        int kvh = slot - 40;
        long poff = ((((long)b * 2 + 1) * 8 + kvh) * 4096 + s) * 128 + pair;
        *(float4*)(present + poff)      = x1;
        *(float4*)(present + poff + 64) = x2;
        long voff = (((long)b * 8 + kvh) * 128 + pair) * 2048 + s;
        Vt[voff]             = f2bf(x1.x);
        Vt[voff + 1 * 2048]  = f2bf(x1.y);
        Vt[voff + 2 * 2048]  = f2bf(x1.z);
        Vt[voff + 3 * 2048]  = f2bf(x1.w);
        Vt[voff + 64 * 2048] = f2bf(x2.x);
        Vt[voff + 65 * 2048] = f2bf(x2.y);
        Vt[voff + 66 * 2048] = f2bf(x2.z);
        Vt[voff + 67 * 2048] = f2bf(x2.w);
    }
}

// ---------------- causal GQA flash attention (R16-proven + T13 defer-max) ------------
// Uniform-work paired q-tiles: block p handles qt=p and qt=15-p -> 34 K-steps every
// block. 512 blocks, 4 waves each, LDS 32KB (Ks 16KB with P alias + Vs 16KB).
// T13: skip the O-rescale when the wave's max-growth <= 8 (P bounded by e^8;
// f32 lst and bf16 P both tolerate). Wave-uniform branch via __any.
// R11: 80KB dbuf regresses (occupancy). R17: QBLK=64 regresses (2x staging volume).
// launch_bounds must stay (256,2): (256,3) caps VGPR ~84 and spills (R5).
__global__ void __launch_bounds__(256, 2)
k_attn(const u16* __restrict__ Qb, const u16* __restrict__ Kb,
       const u16* __restrict__ Vt, u16* __restrict__ attnB)
{
    __shared__ __align__(16) u16 Ks[64 * 128];   // [key][d] chunk16 swz; P alias after QK
    __shared__ __align__(16) u16 Vs[128 * 64];   // [d][key], chunk8 swz ^(row&7)
    const int l = threadIdx.x & 63;
    const int w = threadIdx.x >> 6;
    const int h = blockIdx.y, b = blockIdx.z;
    const int p = blockIdx.x;
    const int kvh = h >> 2;
    u16* Psw = &Ks[w * 2048];                    // per-wave 32x64 P, aliases K tile

    const long kbase = ((long)b * 8 + kvh) * (2048L * 128);
    const long vbase = ((long)b * 8 + kvh) * (128L * 2048);
    f32x4 zero = {0.f, 0.f, 0.f, 0.f};

    for (int half = 0; half < 2; ++half) {
        const int qt = half ? (15 - p) : p;
        const int q0 = qt * 128;

        const long qbase = (((long)b * 32 + h) * 2048 + q0 + w * 32) * 128;
        bf16x8 qf[2][4];
        #pragma unroll
        for (int mi = 0; mi < 2; ++mi)
            #pragma unroll
            for (int kk = 0; kk < 4; ++kk)
                qf[mi][kk] = *(const bf16x8*)(Qb + qbase + (long)(mi * 16 + (l & 15)) * 128
                                              + kk * 32 + ((l >> 4) << 3));

        f32x4 o[2][8];
        float mst[2][4], lst[2][4];
        #pragma unroll
        for (int mi = 0; mi < 2; ++mi) {
            #pragma unroll
            for (int j = 0; j < 8; ++j) o[mi][j] = zero;
            #pragma unroll
            for (int r = 0; r < 4; ++r) { mst[mi][r] = -3.0e38f; lst[mi][r] = 0.f; }
        }

        const int nkt = (q0 >> 6) + 2;  // keys 0 .. q0+127
        for (int kt = 0; kt < nkt; ++kt) {
            const int k0 = kt * 64;
            __syncthreads();
            #pragma unroll
            for (int i = 0; i < 4; ++i) {     // K tile: 16KB, 4 chunks/wave
                int c = w * 4 + i;
                int row = c * 4 + (l >> 4);
                int lg = ((l & 15) ^ (row & 15)) << 3;
                gl_lds16(Kb + kbase + (long)(k0 + row) * 128 + lg, &Ks[c * 512]);
            }
            #pragma unroll
            for (int i = 0; i < 4; ++i) {     // V^T tile: 16KB
                int c = w * 4 + i;
                int row = c * 8 + (l >> 3);
                int lg = ((l & 7) ^ (row & 7)) << 3;
                gl_lds16(Vt + vbase + (long)row * 2048 + k0 + lg, &Vs[c * 512]);
            }
            __syncthreads();

            f32x4 s[2][4];
            #pragma unroll
            for (int mi = 0; mi < 2; ++mi)
                #pragma unroll
                for (int nf = 0; nf < 4; ++nf) s[mi][nf] = zero;
            #pragma unroll
            for (int kk = 0; kk < 4; ++kk) {
                bf16x8 kf[4];
                #pragma unroll
                for (int nf = 0; nf < 4; ++nf) {
                    int row = nf * 16 + (l & 15);
                    int ph = (kk * 4 + (l >> 4)) ^ (row & 15);
                    kf[nf] = *(const bf16x8*)&Ks[row * 128 + ph * 8];
                }
                __builtin_amdgcn_s_setprio(1);
                #pragma unroll
                for (int mi = 0; mi < 2; ++mi)
                    #pragma unroll
                    for (int nf = 0; nf < 4; ++nf)
                        s[mi][nf] = mfma16(qf[mi][kk], kf[nf], s[mi][nf]);
                __builtin_amdgcn_s_setprio(0);
            }
            #pragma unroll
            for (int mi = 0; mi < 2; ++mi)
                #pragma unroll
                for (int nf = 0; nf < 4; ++nf)
                    #pragma unroll
                    for (int r = 0; r < 4; ++r) {
                        int rowg = q0 + w * 32 + mi * 16 + ((l >> 4) << 2) + r;
                        int colg = k0 + nf * 16 + (l & 15);
                        if (colg > rowg) s[mi][nf][r] = -1.0e30f;
                    }
            // ---- online softmax with T13 defer-max ----
            float tmax[2][4];
            float need = -3.0e38f;
            #pragma unroll
            for (int mi = 0; mi < 2; ++mi)
                #pragma unroll
                for (int r = 0; r < 4; ++r) {
                    float t = fmaxf(fmaxf(s[mi][0][r], s[mi][1][r]),
                                    fmaxf(s[mi][2][r], s[mi][3][r]));
                    t = fmaxf(t, __shfl_xor(t, 1));
                    t = fmaxf(t, __shfl_xor(t, 2));
                    t = fmaxf(t, __shfl_xor(t, 4));
                    t = fmaxf(t, __shfl_xor(t, 8));
                    tmax[mi][r] = t;
                    need = fmaxf(need, t - mst[mi][r]);
                }
            if (__any(need > 8.0f)) {
                // rescale path: update running max, scale O and lst
                #pragma unroll
                for (int mi = 0; mi < 2; ++mi)
                    #pragma unroll
                    for (int r = 0; r < 4; ++r) {
                        float nm = fmaxf(mst[mi][r], tmax[mi][r]);
                        float sc = __expf(mst[mi][r] - nm);
                        mst[mi][r] = nm;
                        lst[mi][r] *= sc;
                        #pragma unroll
                        for (int nf2 = 0; nf2 < 8; ++nf2) o[mi][nf2][r] *= sc;
                    }
            }  // else: keep old max; P bounded by e^8, f32 lst has headroom
            __syncthreads();  // all waves done READING Ks before P overwrites it
            #pragma unroll
            for (int mi = 0; mi < 2; ++mi)
                #pragma unroll
                for (int nf = 0; nf < 4; ++nf)
                    #pragma unroll
                    for (int r = 0; r < 4; ++r) {
                        float pv = __expf(s[mi][nf][r] - mst[mi][r]);
                        lst[mi][r] += pv;
                        int row = mi * 16 + ((l >> 4) << 2) + r;
                        int col = nf * 16 + (l & 15);
                        Psw[row * 64 + (((col >> 3) ^ (row & 7)) << 3) + (col & 7)] = f2bf(pv);
                    }
            #pragma unroll
            for (int kk2 = 0; kk2 < 2; ++kk2) {
                bf16x8 pa[2];
                #pragma unroll
                for (int mi = 0; mi < 2; ++mi) {
                    int row = mi * 16 + (l & 15);
                    int ph = (kk2 * 4 + (l >> 4)) ^ (row & 7);
                    pa[mi] = *(const bf16x8*)&Psw[row * 64 + ph * 8];
                }
                #pragma unroll
                for (int nf2 = 0; nf2 < 8; ++nf2) {
                    int vrow = nf2 * 16 + (l & 15);
                    int ph = (kk2 * 4 + (l >> 4)) ^ (vrow & 7);
                    bf16x8 vf = *(const bf16x8*)&Vs[vrow * 64 + ph * 8];
                    __builtin_amdgcn_s_setprio(1);
                    #pragma unroll
                    for (int mi = 0; mi < 2; ++mi)
                        o[mi][nf2] = mfma16(pa[mi], vf, o[mi][nf2]);
                    __builtin_amdgcn_s_setprio(0);
                }
            }
        }

        #pragma unroll
        for (int mi = 0; mi < 2; ++mi)
            #pragma unroll
            for (int r = 0; r < 4; ++r) {
                float t = lst[mi][r];
                t += __shfl_xor(t, 1);
                t += __shfl_xor(t, 2);
                t += __shfl_xor(t, 4);
                t += __shfl_xor(t, 8);
                lst[mi][r] = 1.0f / t;
            }
        #pragma unroll
        for (int mi = 0; mi < 2; ++mi)
            #pragma unroll
            for (int nf2 = 0; nf2 < 8; ++nf2)
                #pragma unroll
                for (int r = 0; r < 4; ++r) {
                    long row = (long)b * 2048 + q0 + w * 32 + mi * 16 + ((l >> 4) << 2) + r;
                    attnB[row * 4096 + h * 128 + nf2 * 16 + (l & 15)] =
                        f2bf(o[mi][nf2][r] * lst[mi][r]);
                }
    }
}

extern "C" void kernel_launch(void* const* d_in, const int* in_sizes, int n_in,
                              void* d_out, int out_size, void* d_ws, size_t ws_size,
                              hipStream_t stream)
{
    (void)in_sizes; (void)n_in; (void)out_size; (void)ws_size;
    const float* hidden = (const float*)d_in[0];
    const float* past   = (const float*)d_in[1];
    const float* cosb   = (const float*)d_in[2];
    const float* sinb   = (const float*)d_in[3];
    const float* Wq     = (const float*)d_in[4];
    const float* Wk     = (const float*)d_in[5];
    const float* Wv     = (const float*)d_in[6];
    const float* Wo     = (const float*)d_in[7];
    float* out     = (float*)d_out;             // (B,S,HID) f32
    float* present = out + 16777216L;           // (B,2,KVH,MAXPOS,D) f32

    // workspace layout (224 MiB total)
    char* ws = (char*)d_ws;
    u16*  hiddenB = (u16*)(ws);                  // 33,554,432 B (later aliased as Qbuf)
    u16*  WqkvT   = (u16*)(ws + 33554432L);      // 50,331,648 B (6144 x 4096 bf16)
    u16*  WoT     = (u16*)(ws + 83886080L);      // 33,554,432 B
    u16*  QKVh    = (u16*)(ws + 117440512L);     // 2 x 50,331,648 B bf16 K-split partials
    u16*  Kb      = (u16*)(ws + 218103808L);     // 8,388,608 B
    u16*  Vt      = (u16*)(ws + 226492416L);     // 8,388,608 B
    u16*  Qbuf    = hiddenB;                     // reuse after QKV GEMM consumed hiddenB
    u16*  attnB   = QKVh;                        // reuse after rope consumed both halves

    static bool attr_done = false;
    if (!attr_done) {
        hipFuncSetAttribute((const void*)k_gemm8ph<1, 2>,
                            hipFuncAttributeMaxDynamicSharedMemorySize, 131072);
        hipFuncSetAttribute((const void*)k_gemm8ph<0, 1>,
                            hipFuncAttributeMaxDynamicSharedMemorySize, 131072);
        attr_done = true;
    }

    // fused prep: cast (16384) + past-tail copy (8192) + weight transposes (40960)
    k_prep<<<65536, 256, 0, stream>>>(hidden, hiddenB, (const float4*)past,
                                      (float4*)present, Wq, Wk, Wv, Wo, WqkvT, WoT);
    // QKV: 8-phase, K-split x2 -> 384 tiles x 2 halves = 768 blocks = 3.0 CU-rounds
    k_gemm8ph<1, 2><<<768, 512, 131072, stream>>>(hiddenB, WqkvT, (void*)QKVh,
                                                  4096, 6144, 4096, 24);
    k_rope_scatter<<<12288, 256, 0, stream>>>(QKVh, cosb, sinb, Qbuf, Kb, Vt, present);
    // attn: paired q-tiles (p, 15-p) -> uniform 34 K-steps/block, 512 blocks
    k_attn<<<dim3(8, 32, 2), 256, 0, stream>>>(Qbuf, Kb, Vt, attnB);
    // Wo: 8-phase, grid 256 = 1.0 CU-rounds, f32 out
    k_gemm8ph<0, 1><<<256, 512, 131072, stream>>>(attnB, WoT, (void*)out,
                                                  4096, 4096, 4096, 16);
}